// Round 9
// baseline (268.649 us; speedup 1.0000x reference)
//
#include <hip/hip_runtime.h>
#include <stdint.h>

#define B_   256
#define O_   128
#define D_   128
#define IN_  16384
#define NEGF (-9.0e15f)
#define TINYF 1.1754943508222875e-38f
#define WGSCOPE __HIP_MEMORY_SCOPE_WORKGROUP

// ---------------- threefry2x32 (JAX partitionable, 20 rounds) ----------------
__device__ __forceinline__ void tf2x32(uint32_t k0, uint32_t k1,
                                       uint32_t x0, uint32_t x1,
                                       uint32_t* o0, uint32_t* o1) {
  uint32_t k2 = k0 ^ k1 ^ 0x1BD11BDAu;
#define TFR(r) { x0 += x1; x1 = (x1 << (r)) | (x1 >> (32 - (r))); x1 ^= x0; }
  x0 += k0; x1 += k1;
  TFR(13) TFR(15) TFR(26) TFR(6)
  x0 += k1; x1 += k2 + 1u;
  TFR(17) TFR(29) TFR(16) TFR(24)
  x0 += k2; x1 += k0 + 2u;
  TFR(13) TFR(15) TFR(26) TFR(6)
  x0 += k0; x1 += k1 + 3u;
  TFR(17) TFR(29) TFR(16) TFR(24)
  x0 += k1; x1 += k2 + 4u;
  TFR(13) TFR(15) TFR(26) TFR(6)
  x0 += k2; x1 += k0 + 5u;
#undef TFR
  *o0 = x0; *o1 = x1;
}

__device__ __forceinline__ float gumbel_bits(uint32_t bits) {
  float f = __uint_as_float((bits >> 9) | 0x3f800000u) - 1.0f;  // [0,1)
  float u = fmaxf(TINYF, f + TINYF);
  return -logf(-logf(u));
}

__device__ __forceinline__ uint32_t mono32(float x) {
  int b = __float_as_int(x);
  return (uint32_t)b ^ ((uint32_t)(b >> 31) | 0x80000000u);
}

__device__ __forceinline__ float rl_f(float v, int l) {
  return __int_as_float(__builtin_amdgcn_readlane(__float_as_int(v), l));
}
__device__ __forceinline__ uint64_t rl_u64(uint64_t v, int l) {
  uint32_t lo = (uint32_t)__builtin_amdgcn_readlane((int)(uint32_t)v, l);
  uint32_t hi = (uint32_t)__builtin_amdgcn_readlane((int)(uint32_t)(v >> 32), l);
  return ((uint64_t)hi << 32) | lo;
}

// DPP reductions: xor1,2,4,8 butterfly + row_bcast15/31 funnel into lane 63.
// Bitwise-identical to the round-5..8 passing trajectory.
#define DPPF(x, ctrl) __int_as_float(__builtin_amdgcn_mov_dpp( \
    __float_as_int(x), (ctrl), 0xf, 0xf, true))

__device__ __forceinline__ float wredmaxf(float x) {
  x = fmaxf(x, DPPF(x, 0xB1));
  x = fmaxf(x, DPPF(x, 0x4E));
  x = fmaxf(x, DPPF(x, 0x141));
  x = fmaxf(x, DPPF(x, 0x140));
  x = fmaxf(x, DPPF(x, 0x142));   // row_bcast15
  x = fmaxf(x, DPPF(x, 0x143));   // row_bcast31
  return rl_f(x, 63);
}
__device__ __forceinline__ float wredsumf(float x) {
  x = x + DPPF(x, 0xB1);
  x = x + DPPF(x, 0x4E);
  x = x + DPPF(x, 0x141);
  x = x + DPPF(x, 0x140);
  x = x + DPPF(x, 0x142);
  x = x + DPPF(x, 0x143);
  return rl_f(x, 63);
}

// ---------------- Kernel A: M[b][p][o] = <enc[b,p,:], W[o, p*D:(p+1)*D]> ----
__global__ __launch_bounds__(256, 1) void build_M(
    const float* __restrict__ enc, const float* __restrict__ W,
    float* __restrict__ M) {
  const int p  = blockIdx.x;
  const int b0 = blockIdx.y * 128;
  const int t  = threadIdx.x;

  __shared__ float Ws[128 * 132];
  __shared__ float Es[128 * 132];

  {
    const int rgrp = t >> 5;      // 8 rows per iteration
    const int c16  = t & 31;      // float4 index within a 512B row
#pragma unroll
    for (int k = 0; k < 16; k++) {
      int row = k * 8 + rgrp;
      *(float4*)(Ws + row * 132 + c16 * 4) =
          *(const float4*)(W + (size_t)row * IN_ + p * D_ + c16 * 4);
    }
#pragma unroll
    for (int k = 0; k < 16; k++) {
      int row = k * 8 + rgrp;
      *(float4*)(Es + row * 132 + c16 * 4) =
          *(const float4*)(enc + ((size_t)(b0 + row) * O_ + p) * D_ + c16 * 4);
    }
  }
  __syncthreads();

  const int og = t & 15, bg = t >> 4;
  float acc0[8][8] = {}, acc1[8][8] = {};

  for (int dc = 0; dc < 128; dc += 4) {
    float4 wv[8], ev[8];
#pragma unroll
    for (int oi = 0; oi < 8; oi++)
      wv[oi] = *(const float4*)(Ws + (og + 16 * oi) * 132 + dc);
#pragma unroll
    for (int bi = 0; bi < 8; bi++)
      ev[bi] = *(const float4*)(Es + (bg + 16 * bi) * 132 + dc);
#pragma unroll
    for (int bi = 0; bi < 8; bi++)
#pragma unroll
      for (int oi = 0; oi < 8; oi++) {
        acc0[bi][oi] += ev[bi].x * wv[oi].x;
        acc1[bi][oi] += ev[bi].y * wv[oi].y;
        acc0[bi][oi] += ev[bi].z * wv[oi].z;
        acc1[bi][oi] += ev[bi].w * wv[oi].w;
      }
  }
#pragma unroll
  for (int bi = 0; bi < 8; bi++) {
    int b = b0 + bg + 16 * bi;
#pragma unroll
    for (int oi = 0; oi < 8; oi++) {
      int o = og + 16 * oi;
      M[((size_t)b * O_ + p) * O_ + o] = acc0[bi][oi] + acc1[bi][oi];
    }
  }
}

// ---------------- Kernel S: fused sampler, 4 waves ---------------------------
// wave0 = serial consumer (ALONE on its SIMD). waves1-3: produce all G rows,
// then become rank/err/ls workers on LDS snapshots (their own SIMDs).
__global__ __launch_bounds__(256, 1) void sampler(
    const float* __restrict__ M, const float* __restrict__ bias,
    const float* __restrict__ enc, const float* __restrict__ W, int use_M,
    float* __restrict__ out_pos, float* __restrict__ out_ls,
    float* __restrict__ out_err) {
  const int b = blockIdx.x;
  const int t = threadIdx.x;
  const int lane = t & 63;
  const int w = t >> 6;

  __shared__ float  Mlds[O_ * O_];          // 64 KB
  __shared__ float  Glds[O_ * O_];          // 64 KB
  __shared__ double snapPd[16 * 64 * 2];    // 16 KB
  __shared__ unsigned long long snapMk[16 * 2];
  __shared__ double lsSlot[16];
  __shared__ int    errSlot[16];
  __shared__ int    posb[O_];
  __shared__ int    flags[O_];
  __shared__ int    doneChunk, chunksDone;

  if (use_M) {
    const float4* src = (const float4*)(M + (size_t)b * O_ * O_);
    for (int i = t; i < O_ * O_ / 4; i += 256) ((float4*)Mlds)[i] = src[i];
  } else {
    for (int idx = t; idx < O_ * O_; idx += 256) {
      int p = idx >> 7, o = idx & 127;
      const float* er = enc + ((size_t)b * O_ + p) * D_;
      const float* wr = W + (size_t)o * IN_ + p * D_;
      float s = 0.f;
      for (int d = 0; d < D_; d += 4) {
        float4 e4 = *(const float4*)(er + d);
        float4 w4 = *(const float4*)(wr + d);
        s += e4.x * w4.x + e4.y * w4.y + e4.z * w4.z + e4.w * w4.w;
      }
      Mlds[idx] = s;
    }
  }
  if (t < O_) flags[t] = 0;
  if (t == 0) { doneChunk = 0; chunksDone = 0; }
  __syncthreads();

  if (w == 0) {
    // ================== consumer: the serial decision chain ==================
    __builtin_amdgcn_s_setprio(3);
#define WAITF(r) { int _n = 0; \
    while (__hip_atomic_load(&flags[r], __ATOMIC_ACQUIRE, WGSCOPE) == 0 && \
           _n < (1 << 26)) { _n++; __builtin_amdgcn_s_sleep(1); } }
    double Pd1 = 0.0, Pd2 = 0.0;
    for (int p = 0; p < O_; p++) {
      Pd1 += (double)Mlds[p * O_ + lane];
      Pd2 += (double)Mlds[p * O_ + 64 + lane];
    }
    const float b1f = bias[lane], b2f = bias[lane + 64];
    int mk1 = 0, mk2 = 0;
    unsigned long long bmk1 = 0ull, bmk2 = 0ull;

    WAITF(7); WAITF(8); WAITF(9);    // 3 in-order producers => rows 0..9 ready
    float g1c = Glds[lane],      g2c = Glds[64 + lane];
    float g1n = Glds[O_ + lane], g2n = Glds[O_ + 64 + lane];

    for (int j = 0; j < O_; j++) {
      if ((j & 7) == 0) {
        if (j) {  // 3 consecutive flags => all rows <= j+9 produced
          int rA = j + 7, rB = j + 8, rC = j + 9;
          if (rC > 127) { rA = 125; rB = 126; rC = 127; }
          WAITF(rA); WAITF(rB); WAITF(rC);
        }
        int c = j >> 3;   // snapshot state entering step 8c
        double2 pv; pv.x = Pd1; pv.y = Pd2;
        *(double2*)&snapPd[(c * 64 + lane) * 2] = pv;
        if (lane == 0) { snapMk[c * 2] = bmk1; snapMk[c * 2 + 1] = bmk2; }
      }
      // exact reference op order (bit-identical trajectory to rounds 5-8)
      float pm1 = mk1 ? NEGF : ((float)Pd1 + b1f);
      float pm2 = mk2 ? NEGF : ((float)Pd2 + b2f);
      float mx = wredmaxf(fmaxf(pm1, pm2));
      float s1 = pm1 - mx, s2 = pm2 - mx;
      float ss = wredsumf(expf(s1) + expf(s2));
      float lse = logf(ss);
      float y1 = (s1 - lse) + g1c;
      float y2 = (s2 - lse) + g2c;
      float ym = wredmaxf(fmaxf(y1, y2));
      unsigned long long bal1 = __ballot(y1 == ym);
      unsigned long long bal2 = __ballot(y2 == ym);
      int pos = bal1 ? (__ffsll(bal1) - 1) : (64 + __ffsll(bal2) - 1);

      if (lane == 0) posb[j] = pos;
      mk1 |= (lane == pos);
      mk2 |= (lane + 64 == pos);
      if (pos < 64) bmk1 |= 1ull << pos; else bmk2 |= 1ull << (pos - 64);
      Pd1 -= (double)Mlds[pos * O_ + lane];
      Pd2 -= (double)Mlds[pos * O_ + 64 + lane];
      if ((j & 7) == 7 && lane == 0)
        __hip_atomic_store(&doneChunk, (j >> 3) + 1, __ATOMIC_RELEASE, WGSCOPE);

      g1c = g1n; g2c = g2n;
      int r = j + 2;
      if (r < O_) {
        g1n = Glds[r * O_ + lane];
        g2n = Glds[r * O_ + 64 + lane];
      }
    }
#undef WAITF
    // positions written once (column i = posb[127-i])
    out_pos[(size_t)b * O_ + lane]      = (float)posb[127 - lane];
    out_pos[(size_t)b * O_ + 64 + lane] = (float)posb[63 - lane];
    return;
  }

  // ================== waves 1-3: producers, then workers =====================
  for (int r = w - 1; r < O_; r += 3) {
    uint32_t k0j, k1j, w0, w1;
    tf2x32(0u, 42u, 0u, (uint32_t)r, &k0j, &k1j);
    uint32_t m1 = (uint32_t)(b * O_ + lane);
    tf2x32(k0j, k1j, 0u, m1, &w0, &w1);
    float g1 = gumbel_bits(w0 ^ w1);
    tf2x32(k0j, k1j, 0u, m1 + 64u, &w0, &w1);
    float g2 = gumbel_bits(w0 ^ w1);
    Glds[r * O_ + lane] = g1;
    Glds[r * O_ + 64 + lane] = g2;
    if (lane == 0)
      __hip_atomic_store(&flags[r], 1, __ATOMIC_RELEASE, WGSCOPE);
  }

  {
    const float b1f = bias[lane], b2f = bias[lane + 64];
    for (int c = w - 1; c < 16; c += 3) {
      int n = 0;
      while (__hip_atomic_load(&doneChunk, __ATOMIC_ACQUIRE, WGSCOPE) < c + 1 &&
             n < (1 << 26)) { n++; __builtin_amdgcn_s_sleep(8); }
      double2 pv = *(double2*)&snapPd[(c * 64 + lane) * 2];
      double Pd1 = pv.x, Pd2 = pv.y;
      unsigned long long bmk1 = snapMk[c * 2], bmk2 = snapMk[c * 2 + 1];
      double ls_acc = 0.0;
      int err_acc = 0;
      for (int j = 8 * c; j < 8 * c + 8; j++) {
        float p1 = (float)Pd1 + b1f;   // bit-identical to consumer's score
        float p2 = (float)Pd2 + b2f;
        // rank: u64 keys (mono<<7)|(127-idx); > means better, idx tie-break
        uint64_t K1 = ((uint64_t)mono32(p1) << 7) | (uint32_t)(127 - lane);
        uint64_t K2 = ((uint64_t)mono32(p2) << 7) | (uint32_t)(63 - lane);
        int c1 = 0, c2 = 0;
#pragma unroll 8
        for (int q = 0; q < 64; q++) {
          uint64_t s1v = rl_u64(K1, q), s2v = rl_u64(K2, q);
          c1 += (s1v > K1) ? 1 : 0;
          c1 += (s2v > K1) ? 1 : 0;
          c2 += (s1v > K2) ? 1 : 0;
          c2 += (s2v > K2) ? 1 : 0;
        }
        unsigned long long t1 = __ballot(c1 == j), t2 = __ballot(c2 == j);
        int topl, msk;
        if (t1) { topl = __ffsll(t1) - 1; msk = (int)((bmk1 >> topl) & 1); }
        else    { topl = __ffsll(t2) - 1; msk = (int)((bmk2 >> topl) & 1); }
        err_acc += msk;

        // ls: identical DPP trees / op order as rounds 2-8 (bit-identical)
        float pm1 = ((bmk1 >> lane) & 1) ? NEGF : p1;
        float pm2 = ((bmk2 >> lane) & 1) ? NEGF : p2;
        float mx = wredmaxf(fmaxf(pm1, pm2));
        float ss = wredsumf(expf(pm1 - mx) + expf(pm2 - mx));
        float lse = logf(ss);
        int pos = posb[j];
        float psel = rl_f((pos < 64) ? p1 : p2, pos & 63);
        ls_acc += (double)((psel - mx) - lse);

        // advance state
        if (pos < 64) bmk1 |= 1ull << pos; else bmk2 |= 1ull << (pos - 64);
        Pd1 -= (double)Mlds[pos * O_ + lane];
        Pd2 -= (double)Mlds[pos * O_ + 64 + lane];
      }
      if (lane == 0) {
        lsSlot[c] = ls_acc;
        errSlot[c] = err_acc;
        int prev = __hip_atomic_fetch_add(&chunksDone, 1, __ATOMIC_ACQ_REL,
                                          WGSCOPE);
        if (prev == 15) {
          double lt = 0.0; int et = 0;
          for (int i = 0; i < 16; i++) { lt += lsSlot[i]; et += errSlot[i]; }
          out_ls[b]  = (float)lt;
          out_err[b] = (float)et;
        }
      }
    }
  }
}

extern "C" void kernel_launch(void* const* d_in, const int* in_sizes, int n_in,
                              void* d_out, int out_size, void* d_ws, size_t ws_size,
                              hipStream_t stream) {
  const float* enc  = (const float*)d_in[0];
  const float* W    = (const float*)d_in[1];
  const float* bias = (const float*)d_in[2];
  float* out     = (float*)d_out;
  float* out_pos = out;                  // [256][128] positions (as f32)
  float* out_ls  = out + B_ * O_;        // [256]
  float* out_err = out + B_ * O_ + B_;   // [256]

  float* M = (float*)d_ws;
  const size_t needM = (size_t)B_ * O_ * O_ * sizeof(float);  // 16.7 MB
  int use_M = (ws_size >= needM) ? 1 : 0;

  if (use_M) build_M<<<dim3(O_, 2), 256, 0, stream>>>(enc, W, M);
  sampler<<<dim3(B_), 256, 0, stream>>>(M, bias, enc, W, use_M,
                                        out_pos, out_ls, out_err);
}

// Round 10
// 224.264 us; speedup vs baseline: 1.1979x; 1.1979x over previous
//
#include <hip/hip_runtime.h>
#include <stdint.h>

#define B_   256
#define O_   128
#define D_   128
#define IN_  16384
#define NEGF (-9.0e15f)
#define TINYF 1.1754943508222875e-38f

// ---------------- threefry2x32 (JAX partitionable, 20 rounds) ----------------
__device__ __forceinline__ void tf2x32(uint32_t k0, uint32_t k1,
                                       uint32_t x0, uint32_t x1,
                                       uint32_t* o0, uint32_t* o1) {
  uint32_t k2 = k0 ^ k1 ^ 0x1BD11BDAu;
#define TFR(r) { x0 += x1; x1 = (x1 << (r)) | (x1 >> (32 - (r))); x1 ^= x0; }
  x0 += k0; x1 += k1;
  TFR(13) TFR(15) TFR(26) TFR(6)
  x0 += k1; x1 += k2 + 1u;
  TFR(17) TFR(29) TFR(16) TFR(24)
  x0 += k2; x1 += k0 + 2u;
  TFR(13) TFR(15) TFR(26) TFR(6)
  x0 += k0; x1 += k1 + 3u;
  TFR(17) TFR(29) TFR(16) TFR(24)
  x0 += k1; x1 += k2 + 4u;
  TFR(13) TFR(15) TFR(26) TFR(6)
  x0 += k2; x1 += k0 + 5u;
#undef TFR
  *o0 = x0; *o1 = x1;
}

__device__ __forceinline__ float gumbel_bits(uint32_t bits) {
  float f = __uint_as_float((bits >> 9) | 0x3f800000u) - 1.0f;  // [0,1)
  float u = fmaxf(TINYF, f + TINYF);
  return -logf(-logf(u));
}

__device__ __forceinline__ uint32_t mono32(float x) {
  int b = __float_as_int(x);
  return (uint32_t)b ^ ((uint32_t)(b >> 31) | 0x80000000u);
}

__device__ __forceinline__ float rl_f(float v, int l) {
  return __int_as_float(__builtin_amdgcn_readlane(__float_as_int(v), l));
}
__device__ __forceinline__ uint64_t rl_u64(uint64_t v, int l) {
  uint32_t lo = (uint32_t)__builtin_amdgcn_readlane((int)(uint32_t)v, l);
  uint32_t hi = (uint32_t)__builtin_amdgcn_readlane((int)(uint32_t)(v >> 32), l);
  return ((uint64_t)hi << 32) | lo;
}

// DPP reductions (bitwise-identical trees to rounds 5-9 passing trajectory)
#define DPPF(x, ctrl) __int_as_float(__builtin_amdgcn_mov_dpp( \
    __float_as_int(x), (ctrl), 0xf, 0xf, true))

__device__ __forceinline__ float wredmaxf(float x) {
  x = fmaxf(x, DPPF(x, 0xB1));
  x = fmaxf(x, DPPF(x, 0x4E));
  x = fmaxf(x, DPPF(x, 0x141));
  x = fmaxf(x, DPPF(x, 0x140));
  x = fmaxf(x, DPPF(x, 0x142));   // row_bcast15
  x = fmaxf(x, DPPF(x, 0x143));   // row_bcast31
  return rl_f(x, 63);
}
__device__ __forceinline__ float wredsumf(float x) {
  x = x + DPPF(x, 0xB1);
  x = x + DPPF(x, 0x4E);
  x = x + DPPF(x, 0x141);
  x = x + DPPF(x, 0x140);
  x = x + DPPF(x, 0x142);
  x = x + DPPF(x, 0x143);
  return rl_f(x, 63);
}

// ---------------- Kernel A: M[b][p][o] = <enc[b,p,:], W[o, p*D:(p+1)*D]> ----
__global__ __launch_bounds__(256, 1) void build_M(
    const float* __restrict__ enc, const float* __restrict__ W,
    float* __restrict__ M) {
  const int p  = blockIdx.x;
  const int b0 = blockIdx.y * 128;
  const int t  = threadIdx.x;

  __shared__ float Ws[128 * 132];
  __shared__ float Es[128 * 132];

  {
    const int rgrp = t >> 5;
    const int c16  = t & 31;
#pragma unroll
    for (int k = 0; k < 16; k++) {
      int row = k * 8 + rgrp;
      *(float4*)(Ws + row * 132 + c16 * 4) =
          *(const float4*)(W + (size_t)row * IN_ + p * D_ + c16 * 4);
    }
#pragma unroll
    for (int k = 0; k < 16; k++) {
      int row = k * 8 + rgrp;
      *(float4*)(Es + row * 132 + c16 * 4) =
          *(const float4*)(enc + ((size_t)(b0 + row) * O_ + p) * D_ + c16 * 4);
    }
  }
  __syncthreads();

  const int og = t & 15, bg = t >> 4;
  float acc0[8][8] = {}, acc1[8][8] = {};

  for (int dc = 0; dc < 128; dc += 4) {
    float4 wv[8], ev[8];
#pragma unroll
    for (int oi = 0; oi < 8; oi++)
      wv[oi] = *(const float4*)(Ws + (og + 16 * oi) * 132 + dc);
#pragma unroll
    for (int bi = 0; bi < 8; bi++)
      ev[bi] = *(const float4*)(Es + (bg + 16 * bi) * 132 + dc);
#pragma unroll
    for (int bi = 0; bi < 8; bi++)
#pragma unroll
      for (int oi = 0; oi < 8; oi++) {
        acc0[bi][oi] += ev[bi].x * wv[oi].x;
        acc1[bi][oi] += ev[bi].y * wv[oi].y;
        acc0[bi][oi] += ev[bi].z * wv[oi].z;
        acc1[bi][oi] += ev[bi].w * wv[oi].w;
      }
  }
#pragma unroll
  for (int bi = 0; bi < 8; bi++) {
    int b = b0 + bg + 16 * bi;
#pragma unroll
    for (int oi = 0; oi < 8; oi++) {
      int o = og + 16 * oi;
      M[((size_t)b * O_ + p) * O_ + o] = acc0[bi][oi] + acc1[bi][oi];
    }
  }
}

// ---------------- Kernel S: phase-separated sampler, 8 waves -----------------
// Phase 0: stage M (interleaved).  Phase 1: waves1-7 produce all gumbels,
// wave0 inits Pd.  Phase 2: wave0 runs the serial chain ALONE (others parked
// at barrier).  Phase 3: all 8 waves do rank/err/ls chunks from snapshots.
__global__ __launch_bounds__(512, 1) void sampler(
    const float* __restrict__ M, const float* __restrict__ bias,
    const float* __restrict__ enc, const float* __restrict__ W, int use_M,
    float* __restrict__ out_pos, float* __restrict__ out_ls,
    float* __restrict__ out_err) {
  const int b = blockIdx.x;
  const int t = threadIdx.x;
  const int lane = t & 63;
  const int w = t >> 6;

  // interleaved: Mlds[p*128 + 2*k + h] = M[b][p][h*64+k]  (h=0/1, k=lane)
  __shared__ float  Mlds[O_ * O_];          // 64 KB
  __shared__ float  Glds[O_ * O_];          // 64 KB, Glds[j*128+2*lane+h]
  __shared__ double snapPd[16 * 64 * 2];    // 16 KB
  __shared__ unsigned long long snapMk[16 * 2];
  __shared__ double lsSlot[16];
  __shared__ int    errSlot[16];
  __shared__ int    posb[O_];

  const float b1f = bias[lane], b2f = bias[lane + 64];

  // ---------- phase 0: stage M into interleaved layout ----------
  if (use_M) {
    const float4* src = (const float4*)(M + (size_t)b * O_ * O_);
    for (int i = t; i < O_ * O_ / 4; i += 512) {
      float4 v = src[i];
      int p = i >> 5, o0 = (i & 31) * 4;
      int h = o0 >> 6, k = o0 & 63;
      float* d = Mlds + p * O_ + 2 * k + h;
      d[0] = v.x; d[2] = v.y; d[4] = v.z; d[6] = v.w;
    }
  } else {
    for (int idx = t; idx < O_ * O_; idx += 512) {
      int p = idx >> 7, o = idx & 127;
      const float* er = enc + ((size_t)b * O_ + p) * D_;
      const float* wr = W + (size_t)o * IN_ + p * D_;
      float s = 0.f;
      for (int d = 0; d < D_; d += 4) {
        float4 e4 = *(const float4*)(er + d);
        float4 w4 = *(const float4*)(wr + d);
        s += e4.x * w4.x + e4.y * w4.y + e4.z * w4.z + e4.w * w4.w;
      }
      Mlds[p * O_ + ((o & 63) << 1) + (o >> 6)] = s;
    }
  }
  __syncthreads();

  // ---------- phase 1: gumbel production (waves 1-7) / Pd init (wave 0) -----
  double Pd1 = 0.0, Pd2 = 0.0;
  if (w == 0) {
    for (int p = 0; p < O_; p++) {
      float2 mv = *(float2*)&Mlds[p * O_ + 2 * lane];
      Pd1 += (double)mv.x;
      Pd2 += (double)mv.y;
    }
  } else {
    for (int r = w - 1; r < O_; r += 7) {
      uint32_t k0j, k1j, w0, w1;
      tf2x32(0u, 42u, 0u, (uint32_t)r, &k0j, &k1j);
      uint32_t m1 = (uint32_t)(b * O_ + lane);
      tf2x32(k0j, k1j, 0u, m1, &w0, &w1);
      float g1 = gumbel_bits(w0 ^ w1);
      tf2x32(k0j, k1j, 0u, m1 + 64u, &w0, &w1);
      float g2 = gumbel_bits(w0 ^ w1);
      float2 gv; gv.x = g1; gv.y = g2;
      *(float2*)&Glds[r * O_ + 2 * lane] = gv;
    }
  }
  __syncthreads();

  // ---------- phase 2: serial chain, wave 0 only (others park at barrier) ---
  if (w == 0) {
    int mk1 = 0, mk2 = 0;
    unsigned long long bmk1 = 0ull, bmk2 = 0ull;
    const float NINF = __int_as_float(0xff800000);
    float2 gcur = *(float2*)&Glds[2 * lane];

    for (int j = 0; j < O_; j++) {
      if ((j & 7) == 0) {        // snapshot state entering chunk j/8
        int c = j >> 3;
        double2 pv; pv.x = Pd1; pv.y = Pd2;
        *(double2*)&snapPd[(c * 64 + lane) * 2] = pv;
        if (lane == 0) { snapMk[c * 2] = bmk1; snapMk[c * 2 + 1] = bmk2; }
      }
      float pm1 = mk1 ? NEGF : ((float)Pd1 + b1f);
      float pm2 = mk2 ? NEGF : ((float)Pd2 + b2f);
      float2 gnext;
      if (j < O_ - 1) gnext = *(float2*)&Glds[(j + 1) * O_ + 2 * lane];

      // gumbel-max shortcut: argmax(pm+g) == argmax((pm-mx-lse)+g) unless the
      // top-2 gap is within fp-rounding (~5e-6); guard with 1e-4 + uniqueness.
      float z1 = pm1 + gcur.x, z2 = pm2 + gcur.y;
      float zm = wredmaxf(fmaxf(z1, z2));
      float e1 = (z1 == zm) ? NINF : z1;
      float e2 = (z2 == zm) ? NINF : z2;
      float sm = wredmaxf(fmaxf(e1, e2));
      unsigned long long bal1 = __ballot(z1 == zm);
      unsigned long long bal2 = __ballot(z2 == zm);
      int nm = __popcll(bal1) + __popcll(bal2);
      int pos;
      if (nm == 1 && (zm - sm) >= 1e-4f) {
        pos = bal1 ? (__ffsll(bal1) - 1) : (64 + __ffsll(bal2) - 1);
      } else {
        // exact reference op order (bit-identical to rounds 5-9)
        float mx = wredmaxf(fmaxf(pm1, pm2));
        float s1 = pm1 - mx, s2 = pm2 - mx;
        float ss = wredsumf(expf(s1) + expf(s2));
        float lse = logf(ss);
        float y1 = (s1 - lse) + gcur.x;
        float y2 = (s2 - lse) + gcur.y;
        float ym = wredmaxf(fmaxf(y1, y2));
        unsigned long long c1 = __ballot(y1 == ym);
        unsigned long long c2 = __ballot(y2 == ym);
        pos = c1 ? (__ffsll(c1) - 1) : (64 + __ffsll(c2) - 1);
      }

      if (lane == 0) posb[j] = pos;
      mk1 |= (lane == pos);
      mk2 |= (lane + 64 == pos);
      if (pos < 64) bmk1 |= 1ull << pos; else bmk2 |= 1ull << (pos - 64);
      float2 mv = *(float2*)&Mlds[pos * O_ + 2 * lane];
      Pd1 -= (double)mv.x;
      Pd2 -= (double)mv.y;
      gcur = gnext;
    }
    // positions written once (column i = posb[127-i])
    out_pos[(size_t)b * O_ + lane]      = (float)posb[127 - lane];
    out_pos[(size_t)b * O_ + 64 + lane] = (float)posb[63 - lane];
  }
  __syncthreads();

  // ---------- phase 3: rank/err/ls chunks, all 8 waves (2 each) -------------
  for (int c = w; c < 16; c += 8) {
    double2 pv = *(double2*)&snapPd[(c * 64 + lane) * 2];
    double P1 = pv.x, P2 = pv.y;
    unsigned long long bmk1 = snapMk[c * 2], bmk2 = snapMk[c * 2 + 1];
    double ls_acc = 0.0;
    int err_acc = 0;
    for (int j = 8 * c; j < 8 * c + 8; j++) {
      float p1 = (float)P1 + b1f;   // bit-identical to consumer's score
      float p2 = (float)P2 + b2f;
      // rank: u64 keys (mono<<7)|(127-idx); > means better, idx tie-break
      uint64_t K1 = ((uint64_t)mono32(p1) << 7) | (uint32_t)(127 - lane);
      uint64_t K2 = ((uint64_t)mono32(p2) << 7) | (uint32_t)(63 - lane);
      int c1 = 0, c2 = 0;
#pragma unroll 8
      for (int q = 0; q < 64; q++) {
        uint64_t s1v = rl_u64(K1, q), s2v = rl_u64(K2, q);
        c1 += (s1v > K1) ? 1 : 0;
        c1 += (s2v > K1) ? 1 : 0;
        c2 += (s1v > K2) ? 1 : 0;
        c2 += (s2v > K2) ? 1 : 0;
      }
      unsigned long long t1 = __ballot(c1 == j), t2 = __ballot(c2 == j);
      int topl, msk;
      if (t1) { topl = __ffsll(t1) - 1; msk = (int)((bmk1 >> topl) & 1); }
      else    { topl = __ffsll(t2) - 1; msk = (int)((bmk2 >> topl) & 1); }
      err_acc += msk;

      // ls: exact reference op order / identical DPP trees
      float pm1 = ((bmk1 >> lane) & 1) ? NEGF : p1;
      float pm2 = ((bmk2 >> lane) & 1) ? NEGF : p2;
      float mx = wredmaxf(fmaxf(pm1, pm2));
      float ss = wredsumf(expf(pm1 - mx) + expf(pm2 - mx));
      float lse = logf(ss);
      int pos = posb[j];
      float psel = rl_f((pos < 64) ? p1 : p2, pos & 63);
      ls_acc += (double)((psel - mx) - lse);

      // advance state
      if (pos < 64) bmk1 |= 1ull << pos; else bmk2 |= 1ull << (pos - 64);
      float2 mv = *(float2*)&Mlds[pos * O_ + 2 * lane];
      P1 -= (double)mv.x;
      P2 -= (double)mv.y;
    }
    if (lane == 0) { lsSlot[c] = ls_acc; errSlot[c] = err_acc; }
  }
  __syncthreads();

  if (t == 0) {
    double lt = 0.0; int et = 0;
    for (int i = 0; i < 16; i++) { lt += lsSlot[i]; et += errSlot[i]; }
    out_ls[b]  = (float)lt;
    out_err[b] = (float)et;
  }
}

extern "C" void kernel_launch(void* const* d_in, const int* in_sizes, int n_in,
                              void* d_out, int out_size, void* d_ws, size_t ws_size,
                              hipStream_t stream) {
  const float* enc  = (const float*)d_in[0];
  const float* W    = (const float*)d_in[1];
  const float* bias = (const float*)d_in[2];
  float* out     = (float*)d_out;
  float* out_pos = out;                  // [256][128] positions (as f32)
  float* out_ls  = out + B_ * O_;        // [256]
  float* out_err = out + B_ * O_ + B_;   // [256]

  float* M = (float*)d_ws;
  const size_t needM = (size_t)B_ * O_ * O_ * sizeof(float);  // 16.7 MB
  int use_M = (ws_size >= needM) ? 1 : 0;

  if (use_M) build_M<<<dim3(O_, 2), 256, 0, stream>>>(enc, W, M);
  sampler<<<dim3(B_), 512, 0, stream>>>(M, bias, enc, W, use_M,
                                        out_pos, out_ls, out_err);
}

// Round 11
// 172.352 us; speedup vs baseline: 1.5587x; 1.3012x over previous
//
#include <hip/hip_runtime.h>
#include <stdint.h>

#define B_   256
#define O_   128
#define D_   128
#define IN_  16384
#define NEGF (-9.0e15f)
#define TINYF 1.1754943508222875e-38f

// ---------------- threefry2x32 (JAX partitionable, 20 rounds) ----------------
__device__ __forceinline__ void tf2x32(uint32_t k0, uint32_t k1,
                                       uint32_t x0, uint32_t x1,
                                       uint32_t* o0, uint32_t* o1) {
  uint32_t k2 = k0 ^ k1 ^ 0x1BD11BDAu;
#define TFR(r) { x0 += x1; x1 = (x1 << (r)) | (x1 >> (32 - (r))); x1 ^= x0; }
  x0 += k0; x1 += k1;
  TFR(13) TFR(15) TFR(26) TFR(6)
  x0 += k1; x1 += k2 + 1u;
  TFR(17) TFR(29) TFR(16) TFR(24)
  x0 += k2; x1 += k0 + 2u;
  TFR(13) TFR(15) TFR(26) TFR(6)
  x0 += k0; x1 += k1 + 3u;
  TFR(17) TFR(29) TFR(16) TFR(24)
  x0 += k1; x1 += k2 + 4u;
  TFR(13) TFR(15) TFR(26) TFR(6)
  x0 += k2; x1 += k0 + 5u;
#undef TFR
  *o0 = x0; *o1 = x1;
}

__device__ __forceinline__ float gumbel_bits(uint32_t bits) {
  float f = __uint_as_float((bits >> 9) | 0x3f800000u) - 1.0f;  // [0,1)
  float u = fmaxf(TINYF, f + TINYF);
  return -logf(-logf(u));
}

__device__ __forceinline__ uint32_t mono32(float x) {
  int b = __float_as_int(x);
  return (uint32_t)b ^ ((uint32_t)(b >> 31) | 0x80000000u);
}

__device__ __forceinline__ float rl_f(float v, int l) {
  return __int_as_float(__builtin_amdgcn_readlane(__float_as_int(v), l));
}

// DPP helpers (identical trees to the rounds 5-10 passing trajectory)
#define DPPF(x, ctrl) __int_as_float(__builtin_amdgcn_mov_dpp( \
    __float_as_int(x), (ctrl), 0xf, 0xf, true))

__device__ __forceinline__ float wredmaxf(float x) {
  x = fmaxf(x, DPPF(x, 0xB1));
  x = fmaxf(x, DPPF(x, 0x4E));
  x = fmaxf(x, DPPF(x, 0x141));
  x = fmaxf(x, DPPF(x, 0x140));
  x = fmaxf(x, DPPF(x, 0x142));   // row_bcast15
  x = fmaxf(x, DPPF(x, 0x143));   // row_bcast31
  return rl_f(x, 63);
}
__device__ __forceinline__ float wredsumf(float x) {
  x = x + DPPF(x, 0xB1);
  x = x + DPPF(x, 0x4E);
  x = x + DPPF(x, 0x141);
  x = x + DPPF(x, 0x140);
  x = x + DPPF(x, 0x142);
  x = x + DPPF(x, 0x143);
  return rl_f(x, 63);
}

// ---------------- Kernel A: M[b][p][o] = <enc[b,p,:], W[o, p*D:(p+1)*D]> ----
__global__ __launch_bounds__(256, 1) void build_M(
    const float* __restrict__ enc, const float* __restrict__ W,
    float* __restrict__ M) {
  const int p  = blockIdx.x;
  const int b0 = blockIdx.y * 128;
  const int t  = threadIdx.x;

  __shared__ float Ws[128 * 132];
  __shared__ float Es[128 * 132];

  {
    const int rgrp = t >> 5;
    const int c16  = t & 31;
#pragma unroll
    for (int k = 0; k < 16; k++) {
      int row = k * 8 + rgrp;
      *(float4*)(Ws + row * 132 + c16 * 4) =
          *(const float4*)(W + (size_t)row * IN_ + p * D_ + c16 * 4);
    }
#pragma unroll
    for (int k = 0; k < 16; k++) {
      int row = k * 8 + rgrp;
      *(float4*)(Es + row * 132 + c16 * 4) =
          *(const float4*)(enc + ((size_t)(b0 + row) * O_ + p) * D_ + c16 * 4);
    }
  }
  __syncthreads();

  const int og = t & 15, bg = t >> 4;
  float acc0[8][8] = {}, acc1[8][8] = {};

  for (int dc = 0; dc < 128; dc += 4) {
    float4 wv[8], ev[8];
#pragma unroll
    for (int oi = 0; oi < 8; oi++)
      wv[oi] = *(const float4*)(Ws + (og + 16 * oi) * 132 + dc);
#pragma unroll
    for (int bi = 0; bi < 8; bi++)
      ev[bi] = *(const float4*)(Es + (bg + 16 * bi) * 132 + dc);
#pragma unroll
    for (int bi = 0; bi < 8; bi++)
#pragma unroll
      for (int oi = 0; oi < 8; oi++) {
        acc0[bi][oi] += ev[bi].x * wv[oi].x;
        acc1[bi][oi] += ev[bi].y * wv[oi].y;
        acc0[bi][oi] += ev[bi].z * wv[oi].z;
        acc1[bi][oi] += ev[bi].w * wv[oi].w;
      }
  }
#pragma unroll
  for (int bi = 0; bi < 8; bi++) {
    int b = b0 + bg + 16 * bi;
#pragma unroll
    for (int oi = 0; oi < 8; oi++) {
      int o = og + 16 * oi;
      M[((size_t)b * O_ + p) * O_ + o] = acc0[bi][oi] + acc1[bi][oi];
    }
  }
}

// ---------------- Kernel S: phase-separated sampler, 8 waves -----------------
__global__ __launch_bounds__(512, 1) void sampler(
    const float* __restrict__ M, const float* __restrict__ bias,
    const float* __restrict__ enc, const float* __restrict__ W, int use_M,
    float* __restrict__ out_pos, float* __restrict__ out_ls,
    float* __restrict__ out_err) {
  const int b = blockIdx.x;
  const int t = threadIdx.x;
  const int lane = t & 63;
  const int w = t >> 6;

  // interleaved: Mlds[p*128 + 2*k + h] = M[b][p][h*64+k]
  __shared__ float  Mlds[O_ * O_];          // 64 KB
  __shared__ float  Glds[O_ * O_];          // 64 KB, Glds[j*128+2*lane+h]
  __shared__ double snapPd[16 * 64 * 2];    // 16 KB
  __shared__ unsigned long long snapMk[16 * 2];
  __shared__ double lsSlot[16];
  __shared__ int    errSlot[16];
  __shared__ int    posb[O_];

  const float b1f = bias[lane], b2f = bias[lane + 64];

  // ---------- phase 0: stage M, conflict-free (coalesced dword loads,
  //            contiguous float2 LDS writes) ----------
  if (use_M) {
    const float* Mb = M + (size_t)b * O_ * O_;
    for (int p = w * 16; p < w * 16 + 16; p++) {
      float v1 = Mb[p * O_ + lane];
      float v2 = Mb[p * O_ + 64 + lane];
      float2 mv; mv.x = v1; mv.y = v2;
      *(float2*)&Mlds[p * O_ + 2 * lane] = mv;
    }
  } else {
    for (int idx = t; idx < O_ * O_; idx += 512) {
      int p = idx >> 7, o = idx & 127;
      const float* er = enc + ((size_t)b * O_ + p) * D_;
      const float* wr = W + (size_t)o * IN_ + p * D_;
      float s = 0.f;
      for (int d = 0; d < D_; d += 4) {
        float4 e4 = *(const float4*)(er + d);
        float4 w4 = *(const float4*)(wr + d);
        s += e4.x * w4.x + e4.y * w4.y + e4.z * w4.z + e4.w * w4.w;
      }
      Mlds[p * O_ + ((o & 63) << 1) + (o >> 6)] = s;
    }
  }
  __syncthreads();

  // ---------- phase 1: gumbels (waves 1-7) / Pd init (wave 0, fixed order) ---
  double Pd1 = 0.0, Pd2 = 0.0;
  if (w == 0) {
    for (int p = 0; p < O_; p++) {
      float2 mv = *(float2*)&Mlds[p * O_ + 2 * lane];
      Pd1 += (double)mv.x;
      Pd2 += (double)mv.y;
    }
  } else {
    for (int r = w - 1; r < O_; r += 7) {
      uint32_t k0j, k1j, w0, w1;
      tf2x32(0u, 42u, 0u, (uint32_t)r, &k0j, &k1j);
      uint32_t m1 = (uint32_t)(b * O_ + lane);
      tf2x32(k0j, k1j, 0u, m1, &w0, &w1);
      float g1 = gumbel_bits(w0 ^ w1);
      tf2x32(k0j, k1j, 0u, m1 + 64u, &w0, &w1);
      float g2 = gumbel_bits(w0 ^ w1);
      float2 gv; gv.x = g1; gv.y = g2;
      *(float2*)&Glds[r * O_ + 2 * lane] = gv;
    }
  }
  __syncthreads();

  // ---------- phase 2: serial chain, wave 0 alone (others parked) ----------
  if (w == 0) {
    __builtin_amdgcn_s_setprio(3);
    int mk1 = 0, mk2 = 0;
    unsigned long long bmk1 = 0ull, bmk2 = 0ull;
    float2 gcur = *(float2*)&Glds[2 * lane];

    for (int j = 0; j < O_; j++) {
      if ((j & 7) == 0) {        // snapshot state entering chunk j/8
        int c = j >> 3;
        double2 pv; pv.x = Pd1; pv.y = Pd2;
        *(double2*)&snapPd[(c * 64 + lane) * 2] = pv;
        if (lane == 0) { snapMk[c * 2] = bmk1; snapMk[c * 2 + 1] = bmk2; }
      }
      float pm1 = mk1 ? NEGF : ((float)Pd1 + b1f);
      float pm2 = mk2 ? NEGF : ((float)Pd2 + b2f);
      float2 gnext;
      if (j < O_ - 1) gnext = *(float2*)&Glds[(j + 1) * O_ + 2 * lane];

      // gumbel-max shortcut on z = pm + g; guard 1e-2 >> max fp divergence
      // (~1.3e-4) between z-ordering and the reference's y-ordering.
      float z1 = pm1 + gcur.x, z2 = pm2 + gcur.y;
      // combined top-2 (max, second) DPP tree; duplicate max => sm==zm => exact path
      float m = fmaxf(z1, z2), s = fminf(z1, z2);
#define MERGE(ctrl) { float om = DPPF(m, ctrl), os = DPPF(s, ctrl); \
      float nm = fmaxf(m, om); \
      float ns = fmaxf(fminf(m, om), fmaxf(s, os)); \
      m = nm; s = ns; }
      MERGE(0xB1) MERGE(0x4E) MERGE(0x141) MERGE(0x140) MERGE(0x142) MERGE(0x143)
#undef MERGE
      float zm = rl_f(m, 63), sm = rl_f(s, 63);

      int pos;
      if (zm - sm >= 1e-2f) {
        unsigned long long bal1 = __ballot(z1 == zm);
        unsigned long long bal2 = __ballot(z2 == zm);
        pos = bal1 ? (__ffsll(bal1) - 1) : (64 + __ffsll(bal2) - 1);
      } else {
        // exact reference op order (bit-identical to rounds 5-10)
        float mx = wredmaxf(fmaxf(pm1, pm2));
        float s1 = pm1 - mx, s2 = pm2 - mx;
        float ss = wredsumf(expf(s1) + expf(s2));
        float lse = logf(ss);
        float y1 = (s1 - lse) + gcur.x;
        float y2 = (s2 - lse) + gcur.y;
        float ym = wredmaxf(fmaxf(y1, y2));
        unsigned long long c1 = __ballot(y1 == ym);
        unsigned long long c2 = __ballot(y2 == ym);
        pos = c1 ? (__ffsll(c1) - 1) : (64 + __ffsll(c2) - 1);
      }

      if (lane == 0) posb[j] = pos;
      mk1 |= (lane == pos);
      mk2 |= (lane + 64 == pos);
      if (pos < 64) bmk1 |= 1ull << pos; else bmk2 |= 1ull << (pos - 64);
      float2 mv = *(float2*)&Mlds[pos * O_ + 2 * lane];
      Pd1 -= (double)mv.x;
      Pd2 -= (double)mv.y;
      gcur = gnext;
    }
    out_pos[(size_t)b * O_ + lane]      = (float)posb[127 - lane];
    out_pos[(size_t)b * O_ + 64 + lane] = (float)posb[63 - lane];
  }
  __syncthreads();

  // ---------- phase 3: rank/err/ls chunks, all 8 waves (2 each) -------------
  for (int c = w; c < 16; c += 8) {
    double2 pv = *(double2*)&snapPd[(c * 64 + lane) * 2];
    double P1 = pv.x, P2 = pv.y;
    unsigned long long bmk1 = snapMk[c * 2], bmk2 = snapMk[c * 2 + 1];
    double ls_acc = 0.0;
    int err_acc = 0;
    for (int j = 8 * c; j < 8 * c + 8; j++) {
      float p1 = (float)P1 + b1f;   // bit-identical to consumer's score
      float p2 = (float)P2 + b2f;
      // u64 keys: (mono<<7)|(127-idx); larger = better rank, idx tie-break
      uint64_t K1 = ((uint64_t)mono32(p1) << 7) | (uint32_t)(127 - lane);
      uint64_t K2 = ((uint64_t)mono32(p2) << 7) | (uint32_t)(63 - lane);
      // bitwise (j+1)-th-largest: 39-iteration binary search (exact)
      uint64_t P = 0;
#pragma unroll
      for (int bit = 38; bit >= 0; --bit) {
        uint64_t cand = P | (1ull << bit);
        int c1 = __popcll(__ballot(K1 >= cand));
        int c2 = __popcll(__ballot(K2 >= cand));
        if (c1 + c2 > j) P = cand;   // at least j+1 keys >= cand
      }
      unsigned long long t1 = __ballot(K1 == P), t2 = __ballot(K2 == P);
      int topl, msk;
      if (t1) { topl = __ffsll(t1) - 1; msk = (int)((bmk1 >> topl) & 1); }
      else    { topl = __ffsll(t2) - 1; msk = (int)((bmk2 >> topl) & 1); }
      err_acc += msk;

      // ls: exact reference op order / identical DPP trees
      float pm1 = ((bmk1 >> lane) & 1) ? NEGF : p1;
      float pm2 = ((bmk2 >> lane) & 1) ? NEGF : p2;
      float mx = wredmaxf(fmaxf(pm1, pm2));
      float ss = wredsumf(expf(pm1 - mx) + expf(pm2 - mx));
      float lse = logf(ss);
      int pos = posb[j];
      float psel = rl_f((pos < 64) ? p1 : p2, pos & 63);
      ls_acc += (double)((psel - mx) - lse);

      // advance state
      if (pos < 64) bmk1 |= 1ull << pos; else bmk2 |= 1ull << (pos - 64);
      float2 mv = *(float2*)&Mlds[pos * O_ + 2 * lane];
      P1 -= (double)mv.x;
      P2 -= (double)mv.y;
    }
    if (lane == 0) { lsSlot[c] = ls_acc; errSlot[c] = err_acc; }
  }
  __syncthreads();

  if (t == 0) {
    double lt = 0.0; int et = 0;
    for (int i = 0; i < 16; i++) { lt += lsSlot[i]; et += errSlot[i]; }
    out_ls[b]  = (float)lt;
    out_err[b] = (float)et;
  }
}

extern "C" void kernel_launch(void* const* d_in, const int* in_sizes, int n_in,
                              void* d_out, int out_size, void* d_ws, size_t ws_size,
                              hipStream_t stream) {
  const float* enc  = (const float*)d_in[0];
  const float* W    = (const float*)d_in[1];
  const float* bias = (const float*)d_in[2];
  float* out     = (float*)d_out;
  float* out_pos = out;                  // [256][128] positions (as f32)
  float* out_ls  = out + B_ * O_;        // [256]
  float* out_err = out + B_ * O_ + B_;   // [256]

  float* M = (float*)d_ws;
  const size_t needM = (size_t)B_ * O_ * O_ * sizeof(float);  // 16.7 MB
  int use_M = (ws_size >= needM) ? 1 : 0;

  if (use_M) build_M<<<dim3(O_, 2), 256, 0, stream>>>(enc, W, M);
  sampler<<<dim3(B_), 512, 0, stream>>>(M, bias, enc, W, use_M,
                                        out_pos, out_ls, out_err);
}